// Round 5
// baseline (4000.139 us; speedup 1.0000x reference)
//
#include <hip/hip_runtime.h>
#include <math.h>

#define B_DIM 2048
#define V_DIM 4096
#define H_DIM 1024

// fp32 accumulation emulating OpenBLAS sgemm GEBP: strictly k-sequential FMA
// within KC=384 panels, panel partials combined by fold-left fp32 add in
// ascending panel order. (VERIFIED bit-exact through round 4 — arithmetic
// order load-bearing; do not alter.)
//
// Round 9: launch-bounds arithmetic pinned empirically: cap = 256/arg
// (arg=4 -> 64 regs [spilled], arg=3 -> 84 [spilled], arg=2 -> 128 [fits the
// ~115-120 demand of the 8x8 split-K kernel]). 128 VGPR = 4 waves/SIMD.
// gemm_v restructured to mirror gemm_h's winning shape: one operand in LDS
// (W-tile, padded transposed VGPR staging, conflict-free), the other direct
// from global (A, k-contiguous float4, 16-lane same-address broadcast).
// gemm_h unchanged from round 4 (~208 us) + the (256,2) bound.
#define BM 128
#define BN 128
#define BK 16
#define KC 384            // OpenBLAS SGEMM_DEFAULT_Q
#define NPANEL_H 11       // V = 10*384 + 256
#define NPANEL_V 3        // H = 2*384 + 256
#define LDSS 132          // 128+4 stride for VGPR-staged (padded) LDS tiles

enum { ACC_NONE = 0, ACC_PREACT = 1, ACC_BIAS = 2 };

#define GLD_LDS16(gsrc, ldst)                                                  \
    __builtin_amdgcn_global_load_lds(                                          \
        (const __attribute__((address_space(1))) void*)(gsrc),                 \
        (__attribute__((address_space(3))) void*)(ldst), 16, 0, 0)

// ---------------------------------------------------------------------------
// h-side panel GEMM: P[pan][b][j] = sum_{k in panel} A[b,k] * W[k,j]
// B-tile (W k-rows, row-major) -> LDS via global_load_lds (linear [BK][BN]).
// A read directly from global: float4 along k, 16-lane broadcast per address.
// ---------------------------------------------------------------------------
__global__ __launch_bounds__(256, 2) void gemm_h_panel(
    const float* __restrict__ A,    // [B_DIM, V_DIM]
    const float* __restrict__ W,    // [V_DIM, H_DIM]
    float* __restrict__ P0,         // panel 0 output [B_DIM, H_DIM]
    float* __restrict__ Prest)      // panels 1.. [NPANEL_H-1][B_DIM, H_DIM]
{
    __shared__ float Bs[2][BK][BN];   // 16 KB, unpadded (global_load_lds dest)

    const int bn  = blockIdx.x * BN;
    const int bm  = blockIdx.y * BM;
    const int pan = blockIdx.z;
    const int k0  = pan * KC;
    const int klen = (V_DIM - k0 < KC) ? (V_DIM - k0) : KC;  // 384 or 256
    const int T = klen / BK;                                  // 24 or 16

    const int t  = threadIdx.x;
    const int tx = t & 15;
    const int ty = t >> 4;
    const int wav  = t >> 6;          // 0..3
    const int lane = t & 63;
    const int radd = lane >> 5;       // 0/1: second row of the 2-row issue
    const int cadd = (lane & 31) * 4; // col within row

    // per-lane staging source: rows k0 + wav*4 + {0,1}/{2,3}, cols bn+cadd
    const float* Wsrc = W + (size_t)(k0 + wav * 4 + radd) * H_DIM + bn + cadd;

    // A row bases: this thread's 8 output rows
    const float* A0 = A + (size_t)(bm + ty * 4) * V_DIM + k0;
    const float* A1 = A0 + (size_t)64 * V_DIM;

    float part[8][8];
#pragma unroll
    for (int i = 0; i < 8; i++)
#pragma unroll
        for (int j = 0; j < 8; j++) part[i][j] = 0.0f;

    // prologue: tile 0 -> buffer 0 (each wave stages 4 k-rows in 2 issues)
    GLD_LDS16(Wsrc,              &Bs[0][wav * 4 + 0][0]);
    GLD_LDS16(Wsrc + 2 * H_DIM,  &Bs[0][wav * 4 + 2][0]);

    int cur = 0;
    for (int it = 0; it < T; ++it) {
        __syncthreads();   // drains vmcnt -> Bs[cur] complete; prior reads done
        if (it + 1 < T) {
            const float* Ws = Wsrc + (size_t)(it + 1) * BK * H_DIM;
            GLD_LDS16(Ws,             &Bs[cur ^ 1][wav * 4 + 0][0]);
            GLD_LDS16(Ws + 2 * H_DIM, &Bs[cur ^ 1][wav * 4 + 2][0]);
        }
        const int kb = it * BK;
#pragma unroll
        for (int q = 0; q < 4; ++q) {
            // load A float4 (4 consecutive k) for 8 rows
            float ak[4][8];   // [s][i], all indices compile-time after unroll
#pragma unroll
            for (int i = 0; i < 4; i++) {
                float4 v0 = *(const float4*)(A0 + (size_t)i * V_DIM + kb + q * 4);
                float4 v1 = *(const float4*)(A1 + (size_t)i * V_DIM + kb + q * 4);
                ak[0][i] = v0.x; ak[1][i] = v0.y; ak[2][i] = v0.z; ak[3][i] = v0.w;
                ak[0][i + 4] = v1.x; ak[1][i + 4] = v1.y; ak[2][i + 4] = v1.z; ak[3][i + 4] = v1.w;
            }
#pragma unroll
            for (int s = 0; s < 4; ++s) {
                const int k = q * 4 + s;
                float4 ya = *(const float4*)(&Bs[cur][k][tx * 4]);
                float4 yb = *(const float4*)(&Bs[cur][k][64 + tx * 4]);
                float bb[8] = {ya.x, ya.y, ya.z, ya.w, yb.x, yb.y, yb.z, yb.w};
#pragma unroll
                for (int i = 0; i < 8; i++)
#pragma unroll
                    for (int j = 0; j < 8; j++)
                        part[i][j] = fmaf(ak[s][i], bb[j], part[i][j]);
            }
        }
        cur ^= 1;
    }

    float* Pout = (pan == 0) ? P0 : (Prest + (size_t)(pan - 1) * B_DIM * H_DIM);
#pragma unroll
    for (int i = 0; i < 8; i++) {
        const int row = bm + ((i < 4) ? (ty * 4 + i) : (64 + ty * 4 + (i - 4)));
        float4 lo, hi;
        lo.x = part[i][0]; lo.y = part[i][1]; lo.z = part[i][2]; lo.w = part[i][3];
        hi.x = part[i][4]; hi.y = part[i][5]; hi.z = part[i][6]; hi.w = part[i][7];
        *(float4*)(&Pout[(size_t)row * H_DIM + bn + tx * 4])      = lo;
        *(float4*)(&Pout[(size_t)row * H_DIM + bn + 64 + tx * 4]) = hi;
    }
}

// ---------------------------------------------------------------------------
// v-side panel GEMM: P[pan][b][i] = sum_{k in panel} A[b,k] * W[i,k]  (h@W^T)
// W-tile -> LDS via padded transposed VGPR staging (conflict-free), giving
// Bs[k][j]. A read directly from global: float4 along k, 16-lane broadcast.
// ---------------------------------------------------------------------------
__global__ __launch_bounds__(256, 2) void gemm_v_panel(
    const float* __restrict__ A,    // [B_DIM, H_DIM]
    const float* __restrict__ W,    // [V_DIM, H_DIM]
    float* __restrict__ P0,         // panel 0 output [B_DIM, V_DIM]
    float* __restrict__ Prest)      // panels 1.. [NPANEL_V-1][B_DIM, V_DIM]
{
    __shared__ float Bs[2][BK][LDSS];  // 16.9 KB

    const int bn  = blockIdx.x * BN;   // V cols
    const int bm  = blockIdx.y * BM;   // B rows
    const int pan = blockIdx.z;
    const int k0  = pan * KC;
    const int klen = (H_DIM - k0 < KC) ? (H_DIM - k0) : KC;  // 384 or 256
    const int T = klen / BK;

    const int t  = threadIdx.x;
    const int tx = t & 15;
    const int ty = t >> 4;

    const int s_wr = t >> 1;          // W row (= output col j) 0..127
    const int s_wk = (t & 1) * 8;     // k-half 0 or 8

    const float* Wptr = W + (size_t)(bn + s_wr) * H_DIM + k0 + s_wk;

    // A row bases: this thread's 8 output rows (k-contiguous, broadcast on tx)
    const float* A0 = A + (size_t)(bm + ty * 4) * H_DIM + k0;
    const float* A1 = A0 + (size_t)64 * H_DIM;

    float part[8][8];
#pragma unroll
    for (int i = 0; i < 8; i++)
#pragma unroll
        for (int j = 0; j < 8; j++) part[i][j] = 0.0f;

    // prologue: W tile 0 -> buffer 0 (transposed: Bs[k][j])
    float4 w0 = *(const float4*)(Wptr + 0);
    float4 w1 = *(const float4*)(Wptr + 4);
    Bs[0][s_wk + 0][s_wr] = w0.x;
    Bs[0][s_wk + 1][s_wr] = w0.y;
    Bs[0][s_wk + 2][s_wr] = w0.z;
    Bs[0][s_wk + 3][s_wr] = w0.w;
    Bs[0][s_wk + 4][s_wr] = w1.x;
    Bs[0][s_wk + 5][s_wr] = w1.y;
    Bs[0][s_wk + 6][s_wr] = w1.z;
    Bs[0][s_wk + 7][s_wr] = w1.w;

    int cur = 0;
    for (int it = 0; it < T; ++it) {
        __syncthreads();
        if (it + 1 < T) {
            const int kk = (it + 1) * BK;
            w0 = *(const float4*)(Wptr + kk);
            w1 = *(const float4*)(Wptr + kk + 4);
        }
        const int kb = it * BK;
#pragma unroll
        for (int q = 0; q < 4; ++q) {
            // load A float4 (4 consecutive k) for 8 rows
            float ak[4][8];   // [s][i]
#pragma unroll
            for (int i = 0; i < 4; i++) {
                float4 v0 = *(const float4*)(A0 + (size_t)i * H_DIM + kb + q * 4);
                float4 v1 = *(const float4*)(A1 + (size_t)i * H_DIM + kb + q * 4);
                ak[0][i] = v0.x; ak[1][i] = v0.y; ak[2][i] = v0.z; ak[3][i] = v0.w;
                ak[0][i + 4] = v1.x; ak[1][i + 4] = v1.y; ak[2][i + 4] = v1.z; ak[3][i + 4] = v1.w;
            }
#pragma unroll
            for (int s = 0; s < 4; ++s) {
                const int k = q * 4 + s;
                float4 ya = *(const float4*)(&Bs[cur][k][tx * 4]);
                float4 yb = *(const float4*)(&Bs[cur][k][64 + tx * 4]);
                float bb[8] = {ya.x, ya.y, ya.z, ya.w, yb.x, yb.y, yb.z, yb.w};
#pragma unroll
                for (int i = 0; i < 8; i++)
#pragma unroll
                    for (int j = 0; j < 8; j++)
                        part[i][j] = fmaf(ak[s][i], bb[j], part[i][j]);
            }
        }
        if (it + 1 < T) {
            Bs[cur ^ 1][s_wk + 0][s_wr] = w0.x;
            Bs[cur ^ 1][s_wk + 1][s_wr] = w0.y;
            Bs[cur ^ 1][s_wk + 2][s_wr] = w0.z;
            Bs[cur ^ 1][s_wk + 3][s_wr] = w0.w;
            Bs[cur ^ 1][s_wk + 4][s_wr] = w1.x;
            Bs[cur ^ 1][s_wk + 5][s_wr] = w1.y;
            Bs[cur ^ 1][s_wk + 6][s_wr] = w1.z;
            Bs[cur ^ 1][s_wk + 7][s_wr] = w1.w;
        }
        cur ^= 1;
    }

    float* Pout = (pan == 0) ? P0 : (Prest + (size_t)(pan - 1) * B_DIM * V_DIM);
#pragma unroll
    for (int i = 0; i < 8; i++) {
        const int row = bm + ((i < 4) ? (ty * 4 + i) : (64 + ty * 4 + (i - 4)));
        float4 lo, hi;
        lo.x = part[i][0]; lo.y = part[i][1]; lo.z = part[i][2]; lo.w = part[i][3];
        hi.x = part[i][4]; hi.y = part[i][5]; hi.z = part[i][6]; hi.w = part[i][7];
        *(float4*)(&Pout[(size_t)row * V_DIM + bn + tx * 4])      = lo;
        *(float4*)(&Pout[(size_t)row * V_DIM + bn + 64 + tx * 4]) = hi;
    }
}

// ---------------------------------------------------------------------------
// h-side combine: tot = ((p0+p1)+...)+p10 ascending (bit-exact fold), then
// pre = bh + tot; h = (sigmoid(pre) > U). Hout may alias P0 (each element is
// fully read before its store; one block per row). NO __restrict__ on P0/Hout.
// ---------------------------------------------------------------------------
__global__ __launch_bounds__(256) void combine_h(
    const float* P0,               // [B_DIM, H_DIM] (may alias Hout)
    const float* __restrict__ Prest,
    const float* __restrict__ bh,
    const float* __restrict__ U,
    float* Hout,
    double* __restrict__ acc,      // direct store (single writer) or nullptr
    const int mode)
{
    const int b = blockIdx.x;
    const int c = threadIdx.x * 4;
    const size_t BH  = (size_t)B_DIM * H_DIM;
    const size_t off = (size_t)b * H_DIM + c;

    float4 tot = *(const float4*)(P0 + off);
#pragma unroll
    for (int p = 1; p < NPANEL_H; p++) {
        float4 q = *(const float4*)(Prest + (size_t)(p - 1) * BH + off);
        tot.x += q.x; tot.y += q.y; tot.z += q.z; tot.w += q.w;
    }
    float4 bias = *(const float4*)(bh + c);
    float4 u    = *(const float4*)(U + off);

    float pre[4] = {bias.x + tot.x, bias.y + tot.y, bias.z + tot.z, bias.w + tot.w};
    float bb[4]  = {bias.x, bias.y, bias.z, bias.w};
    float uu[4]  = {u.x, u.y, u.z, u.w};
    float hv[4];
#pragma unroll
    for (int j = 0; j < 4; j++) {
        float pp = 1.0f / (1.0f + expf(-pre[j]));
        hv[j] = (pp > uu[j]) ? 1.0f : 0.0f;
    }
    float4 hout; hout.x = hv[0]; hout.y = hv[1]; hout.z = hv[2]; hout.w = hv[3];
    *(float4*)(Hout + off) = hout;

    if (mode != ACC_NONE) {
        double s = 0.0;
#pragma unroll
        for (int j = 0; j < 4; j++) {
            if (mode == ACC_PREACT) s += (double)hv[j] * (double)pre[j];
            else                    s += (double)hv[j] * (double)bb[j];
        }
#pragma unroll
        for (int offl = 32; offl >= 1; offl >>= 1) s += __shfl_xor(s, offl, 64);
        __shared__ double red[4];
        if ((threadIdx.x & 63) == 0) red[threadIdx.x >> 6] = s;
        __syncthreads();
        if (threadIdx.x == 0) acc[b] = red[0] + red[1] + red[2] + red[3];
    }
}

// ---------------------------------------------------------------------------
// v-side combine: tot = (p0+p1)+p2 ascending; pre = bv + tot; v = (sig > U).
// Vout may alias P0. One block per row; 16 cols/thread in 4 chunks.
// ---------------------------------------------------------------------------
__global__ __launch_bounds__(256) void combine_v(
    const float* P0,               // [B_DIM, V_DIM] (may alias Vout)
    const float* __restrict__ Prest,
    const float* __restrict__ bv,
    const float* __restrict__ U,
    float* Vout,
    double* __restrict__ acc,
    const int mode)
{
    const int b = blockIdx.x;
    const size_t BV = (size_t)B_DIM * V_DIM;
    double s = 0.0;

#pragma unroll
    for (int ch = 0; ch < 4; ++ch) {
        const int c = ch * 1024 + threadIdx.x * 4;
        const size_t off = (size_t)b * V_DIM + c;
        float4 tot = *(const float4*)(P0 + off);
        float4 q1  = *(const float4*)(Prest + off);
        float4 q2  = *(const float4*)(Prest + BV + off);
        tot.x += q1.x; tot.y += q1.y; tot.z += q1.z; tot.w += q1.w;
        tot.x += q2.x; tot.y += q2.y; tot.z += q2.z; tot.w += q2.w;

        float4 bias = *(const float4*)(bv + c);
        float4 u4   = *(const float4*)(U + off);
        float pre[4] = {bias.x + tot.x, bias.y + tot.y, bias.z + tot.z, bias.w + tot.w};
        float uu[4]  = {u4.x, u4.y, u4.z, u4.w};
        float vs[4];
#pragma unroll
        for (int j = 0; j < 4; j++) {
            float pp = 1.0f / (1.0f + expf(-pre[j]));
            vs[j] = (pp > uu[j]) ? 1.0f : 0.0f;
            if (mode == ACC_PREACT) s += (double)vs[j] * (double)pre[j];
        }
        float4 vst; vst.x = vs[0]; vst.y = vs[1]; vst.z = vs[2]; vst.w = vs[3];
        *(float4*)(Vout + off) = vst;
    }

    if (mode != ACC_NONE) {
#pragma unroll
        for (int offl = 32; offl >= 1; offl >>= 1) s += __shfl_xor(s, offl, 64);
        __shared__ double red[4];
        if ((threadIdx.x & 63) == 0) red[threadIdx.x >> 6] = s;
        __syncthreads();
        if (threadIdx.x == 0) acc[b] = red[0] + red[1] + red[2] + red[3];
    }
}

// out[b] = sum_i X[b,i] * w[i] in fp64 (score term; does not feed sampling)
__global__ __launch_bounds__(256) void rowdot_kernel(
    const float* __restrict__ X, const float* __restrict__ w,
    double* __restrict__ out, const int N)
{
    const int b = blockIdx.x;
    const float* row = X + (size_t)b * N;
    double s = 0.0;
    for (int i = threadIdx.x; i < N / 4; i += blockDim.x) {
        float4 x = ((const float4*)row)[i];
        float4 ww = ((const float4*)w)[i];
        s = fma((double)x.x, (double)ww.x, s);
        s = fma((double)x.y, (double)ww.y, s);
        s = fma((double)x.z, (double)ww.z, s);
        s = fma((double)x.w, (double)ww.w, s);
    }
#pragma unroll
    for (int off = 32; off >= 1; off >>= 1) s += __shfl_xor(s, off, 64);
    __shared__ double red[4];
    if ((threadIdx.x & 63) == 0) red[threadIdx.x >> 6] = s;
    __syncthreads();
    if (threadIdx.x == 0) out[b] = red[0] + red[1] + red[2] + red[3];
}

__global__ void finalize_kernel(const double* __restrict__ vb,
                                const double* __restrict__ accpos,
                                const double* __restrict__ acchb,
                                const double* __restrict__ accneg,
                                float* __restrict__ out)
{
    int b = blockIdx.x * blockDim.x + threadIdx.x;
    if (b < B_DIM) out[b] = (float)(vb[b] + accpos[b] - acchb[b] - accneg[b]);
}

extern "C" void kernel_launch(void* const* d_in, const int* in_sizes, int n_in,
                              void* d_out, int out_size, void* d_ws, size_t ws_size,
                              hipStream_t stream) {
    (void)in_sizes; (void)n_in; (void)out_size; (void)ws_size;
    const float* visible = (const float*)d_in[0];
    const float* b_v     = (const float*)d_in[1];
    const float* b_h     = (const float*)d_in[2];
    const float* W       = (const float*)d_in[3];
    const float* u_h0    = (const float*)d_in[4];
    const float* u_v     = (const float*)d_in[5];  // [3, B, V]
    const float* u_h     = (const float*)d_in[6];  // [2, B, H]
    float* out = (float*)d_out;

    float* v_buf   = (float*)d_ws;                               // B*V floats
    float* h_buf   = v_buf + (size_t)B_DIM * V_DIM;              // B*H floats
    double* acc_pos = (double*)(h_buf + (size_t)B_DIM * H_DIM);  // B doubles
    double* acc_hb  = acc_pos + B_DIM;
    double* acc_neg = acc_hb + B_DIM;
    double* vb      = acc_neg + B_DIM;
    // shared extra-panel region: max(10*B*H, 2*B*V) = 21.0M floats (~84 MB)
    float* Pextra   = (float*)(vb + B_DIM);

    dim3 blk(256);
    dim3 gh(H_DIM / BN, B_DIM / BM, NPANEL_H);   // 8 x 16 x 11 = 1408 blocks
    dim3 gv(V_DIM / BN, B_DIM / BM, NPANEL_V);   // 32 x 16 x 3 = 1536 blocks
    dim3 gc(B_DIM);

    rowdot_kernel<<<B_DIM, blk, 0, stream>>>(visible, b_v, vb, V_DIM);

    const size_t UV = (size_t)B_DIM * V_DIM;
    const size_t UH = (size_t)B_DIM * H_DIM;

    // positive phase: h | data, + sum h*pre
    gemm_h_panel<<<gh, blk, 0, stream>>>(visible, W, h_buf, Pextra);
    combine_h<<<gc, blk, 0, stream>>>(h_buf, Pextra, b_h, u_h0, h_buf, acc_pos, ACC_PREACT);
    // k=0
    gemm_v_panel<<<gv, blk, 0, stream>>>(h_buf, W, v_buf, Pextra);
    combine_v<<<gc, blk, 0, stream>>>(v_buf, Pextra, b_v, u_v + 0 * UV, v_buf, nullptr, ACC_NONE);
    // k=1
    gemm_h_panel<<<gh, blk, 0, stream>>>(v_buf, W, h_buf, Pextra);
    combine_h<<<gc, blk, 0, stream>>>(h_buf, Pextra, b_h, u_h + 0 * UH, h_buf, nullptr, ACC_NONE);
    // k=2
    gemm_v_panel<<<gv, blk, 0, stream>>>(h_buf, W, v_buf, Pextra);
    combine_v<<<gc, blk, 0, stream>>>(v_buf, Pextra, b_v, u_v + 1 * UV, v_buf, nullptr, ACC_NONE);
    // k=3: + h.b_h of final h
    gemm_h_panel<<<gh, blk, 0, stream>>>(v_buf, W, h_buf, Pextra);
    combine_h<<<gc, blk, 0, stream>>>(h_buf, Pextra, b_h, u_h + 1 * UH, h_buf, acc_hb, ACC_BIAS);
    // k=4: + sum_i v*pre (negative score)
    gemm_v_panel<<<gv, blk, 0, stream>>>(h_buf, W, v_buf, Pextra);
    combine_v<<<gc, blk, 0, stream>>>(v_buf, Pextra, b_v, u_v + 2 * UV, v_buf, acc_neg, ACC_PREACT);

    finalize_kernel<<<(B_DIM + 255) / 256, blk, 0, stream>>>(vb, acc_pos, acc_hb, acc_neg, out);
}

// Round 6
// 1615.165 us; speedup vs baseline: 2.4766x; 2.4766x over previous
//
#include <hip/hip_runtime.h>
#include <math.h>

#define B_DIM 2048
#define V_DIM 4096
#define H_DIM 1024

// fp32 accumulation emulating OpenBLAS sgemm GEBP: strictly k-sequential FMA
// within KC=384 panels, panel partials combined by fold-left fp32 add in
// ascending panel order. (VERIFIED bit-exact through round 5 — arithmetic
// order load-bearing; do not alter. fmaf(w,h,acc) == fmaf(h,w,acc) bitwise.)
//
// Round 10: lessons pinned: (a) NEVER cap VGPRs below natural demand (4
// forcing attempts -> spills; round-5: gemm_v 128-cap, 3.3 GB scratch
// writes/dispatch). (b) global_load_lds needs a k-major LDS operand; h-side
// has W[k][j] naturally, v-side gets one by transposing h (8 MB, bit-exact).
// gemm_vT mirrors the proven 208-us gemm_h structure exactly.
// (c) __syncthreads drains vmcnt(0) every BK-tile (the known ~25% stall);
// replaced with triple-buffer LDS + raw s_barrier + counted s_waitcnt
// vmcnt(2) + sched_barrier(0) (m201 pattern). 3 buffers => tile t+1's issue
// overwrites t-2's buffer; any wave past barrier t finished compute t-2.
#define BM 128
#define BN 128
#define BK 16
#define KC 384            // OpenBLAS SGEMM_DEFAULT_Q
#define NPANEL_H 11       // V = 10*384 + 256
#define NPANEL_V 3        // H = 2*384 + 256

enum { ACC_NONE = 0, ACC_PREACT = 1, ACC_BIAS = 2 };

#define GLD_LDS16(gsrc, ldst)                                                  \
    __builtin_amdgcn_global_load_lds(                                          \
        (const __attribute__((address_space(1))) void*)(gsrc),                 \
        (__attribute__((address_space(3))) void*)(ldst), 16, 0, 0)

// ---------------------------------------------------------------------------
// h-side panel GEMM: P[pan][b][j] = sum_{k in panel} A[b,k] * W[k,j]
// W k-rows -> LDS via global_load_lds (linear [BK][BN], triple-buffered,
// counted vmcnt). A read direct from global: float4 along k, 16-lane
// broadcast per address. Natural register allocation (no caps).
// ---------------------------------------------------------------------------
__global__ __launch_bounds__(256) void gemm_h_panel(
    const float* __restrict__ A,    // [B_DIM, V_DIM]
    const float* __restrict__ W,    // [V_DIM, H_DIM]
    float* __restrict__ P0,         // panel 0 output [B_DIM, H_DIM]
    float* __restrict__ Prest)      // panels 1.. [NPANEL_H-1][B_DIM, H_DIM]
{
    __shared__ float Bs[3][BK][BN];   // 24 KB, unpadded (global_load_lds dest)

    const int bn  = blockIdx.x * BN;
    const int bm  = blockIdx.y * BM;
    const int pan = blockIdx.z;
    const int k0  = pan * KC;
    const int klen = (V_DIM - k0 < KC) ? (V_DIM - k0) : KC;  // 384 or 256
    const int T = klen / BK;                                  // 24 or 16

    const int t  = threadIdx.x;
    const int tx = t & 15;
    const int ty = t >> 4;
    const int wav  = t >> 6;          // 0..3
    const int lane = t & 63;
    const int radd = lane >> 5;       // 0/1: second row of the 2-row issue
    const int cadd = (lane & 31) * 4; // col within row

    // per-lane staging source: rows k0 + wav*4 + {0,1}/{2,3}, cols bn+cadd
    const float* Wsrc = W + (size_t)(k0 + wav * 4 + radd) * H_DIM + bn + cadd;

    // A row bases: this thread's 8 output rows
    const float* A0 = A + (size_t)(bm + ty * 4) * V_DIM + k0;
    const float* A1 = A0 + (size_t)64 * V_DIM;

    float part[8][8];
#pragma unroll
    for (int i = 0; i < 8; i++)
#pragma unroll
        for (int j = 0; j < 8; j++) part[i][j] = 0.0f;

    // prologue: tile 0 -> buffer 0 (each wave stages 4 k-rows in 2 issues)
    GLD_LDS16(Wsrc,              &Bs[0][wav * 4 + 0][0]);
    GLD_LDS16(Wsrc + 2 * H_DIM,  &Bs[0][wav * 4 + 2][0]);

    int cur = 0, nxt = 1;
    for (int it = 0; it < T; ++it) {
        if (it + 1 < T) {
            const float* Ws = Wsrc + (size_t)(it + 1) * BK * H_DIM;
            GLD_LDS16(Ws,             &Bs[nxt][wav * 4 + 0][0]);
            GLD_LDS16(Ws + 2 * H_DIM, &Bs[nxt][wav * 4 + 2][0]);
            asm volatile("s_waitcnt vmcnt(2)" ::: "memory");  // tile it landed
        } else {
            asm volatile("s_waitcnt vmcnt(0)" ::: "memory");
        }
        __builtin_amdgcn_s_barrier();          // all waves' tile-it loads in
        __builtin_amdgcn_sched_barrier(0);     // no ds_read hoists above this
        const int kb = it * BK;
#pragma unroll
        for (int q = 0; q < 4; ++q) {
            float ak[4][8];   // [s][i], compile-time indices after unroll
#pragma unroll
            for (int i = 0; i < 4; i++) {
                float4 v0 = *(const float4*)(A0 + (size_t)i * V_DIM + kb + q * 4);
                float4 v1 = *(const float4*)(A1 + (size_t)i * V_DIM + kb + q * 4);
                ak[0][i] = v0.x; ak[1][i] = v0.y; ak[2][i] = v0.z; ak[3][i] = v0.w;
                ak[0][i + 4] = v1.x; ak[1][i + 4] = v1.y; ak[2][i + 4] = v1.z; ak[3][i + 4] = v1.w;
            }
#pragma unroll
            for (int s = 0; s < 4; ++s) {
                const int k = q * 4 + s;
                float4 ya = *(const float4*)(&Bs[cur][k][tx * 4]);
                float4 yb = *(const float4*)(&Bs[cur][k][64 + tx * 4]);
                float bb[8] = {ya.x, ya.y, ya.z, ya.w, yb.x, yb.y, yb.z, yb.w};
#pragma unroll
                for (int i = 0; i < 8; i++)
#pragma unroll
                    for (int j = 0; j < 8; j++)
                        part[i][j] = fmaf(ak[s][i], bb[j], part[i][j]);
            }
        }
        cur = nxt;
        nxt = (nxt == 2) ? 0 : nxt + 1;
    }

    float* Pout = (pan == 0) ? P0 : (Prest + (size_t)(pan - 1) * B_DIM * H_DIM);
#pragma unroll
    for (int i = 0; i < 8; i++) {
        const int row = bm + ((i < 4) ? (ty * 4 + i) : (64 + ty * 4 + (i - 4)));
        float4 lo, hi;
        lo.x = part[i][0]; lo.y = part[i][1]; lo.z = part[i][2]; lo.w = part[i][3];
        hi.x = part[i][4]; hi.y = part[i][5]; hi.z = part[i][6]; hi.w = part[i][7];
        *(float4*)(&Pout[(size_t)row * H_DIM + bn + tx * 4])      = lo;
        *(float4*)(&Pout[(size_t)row * H_DIM + bn + 64 + tx * 4]) = hi;
    }
}

// ---------------------------------------------------------------------------
// 64x64 LDS-tiled transpose: hT[c][b] = h[b][c]. Pure copy, bit-exact.
// ---------------------------------------------------------------------------
__global__ __launch_bounds__(256) void transpose_kernel(
    const float* __restrict__ in,   // [B_DIM, H_DIM]
    float* __restrict__ outT)       // [H_DIM, B_DIM]
{
    __shared__ float tile[64][65];
    const int c0 = blockIdx.x * 64;   // H offset
    const int b0 = blockIdx.y * 64;   // B offset
    const int tx = threadIdx.x & 15;
    const int ty = threadIdx.x >> 4;
#pragma unroll
    for (int rr = 0; rr < 4; ++rr) {
        const int row = ty + rr * 16;   // b-local
        float4 v = *(const float4*)(in + (size_t)(b0 + row) * H_DIM + c0 + tx * 4);
        tile[row][tx * 4 + 0] = v.x;
        tile[row][tx * 4 + 1] = v.y;
        tile[row][tx * 4 + 2] = v.z;
        tile[row][tx * 4 + 3] = v.w;
    }
    __syncthreads();
#pragma unroll
    for (int rr = 0; rr < 4; ++rr) {
        const int row = ty + rr * 16;   // h-local
        float4 v;
        v.x = tile[tx * 4 + 0][row];
        v.y = tile[tx * 4 + 1][row];
        v.z = tile[tx * 4 + 2][row];
        v.w = tile[tx * 4 + 3][row];
        *(float4*)(outT + (size_t)(c0 + row) * B_DIM + b0 + tx * 4) = v;
    }
}

// ---------------------------------------------------------------------------
// v-side panel GEMM (mirror of gemm_h): Q[i][b] = sum_k W[i,k] * hT[k,b],
// stored to P[pan][b][i]. hT k-rows -> LDS via global_load_lds; W direct
// from global (float4 along k, 16-lane broadcast). Same k-ascending chain
// as h@W^T (fmaf operands commuted — bitwise identical).
// ---------------------------------------------------------------------------
__global__ __launch_bounds__(256) void gemm_vT_panel(
    const float* __restrict__ Wm,   // [V_DIM, H_DIM]
    const float* __restrict__ hT,   // [H_DIM, B_DIM]
    float* __restrict__ P0,         // panel 0 output [B_DIM, V_DIM]
    float* __restrict__ Prest)      // panels 1.. [NPANEL_V-1][B_DIM, V_DIM]
{
    __shared__ float Bs[3][BK][BN];   // 24 KB, b-cols tile of hT

    const int bi  = blockIdx.x * BM;   // V rows (output i)
    const int bb0 = blockIdx.y * BN;   // B cols (output b)
    const int pan = blockIdx.z;
    const int k0  = pan * KC;
    const int klen = (H_DIM - k0 < KC) ? (H_DIM - k0) : KC;  // 384 or 256
    const int T = klen / BK;

    const int t  = threadIdx.x;
    const int tx = t & 15;
    const int ty = t >> 4;
    const int wav  = t >> 6;
    const int lane = t & 63;
    const int radd = lane >> 5;
    const int cadd = (lane & 31) * 4;

    // staging source: hT rows k0 + wav*4 + {0,1}/{2,3}, cols bb0+cadd
    const float* Hsrc = hT + (size_t)(k0 + wav * 4 + radd) * B_DIM + bb0 + cadd;

    // W row bases: this thread's 8 output i-rows
    const float* W0 = Wm + (size_t)(bi + ty * 4) * H_DIM + k0;
    const float* W1 = W0 + (size_t)64 * H_DIM;

    float part[8][8];   // [i][j]: i = V-row, j = b-col
#pragma unroll
    for (int i = 0; i < 8; i++)
#pragma unroll
        for (int j = 0; j < 8; j++) part[i][j] = 0.0f;

    GLD_LDS16(Hsrc,              &Bs[0][wav * 4 + 0][0]);
    GLD_LDS16(Hsrc + 2 * B_DIM,  &Bs[0][wav * 4 + 2][0]);

    int cur = 0, nxt = 1;
    for (int it = 0; it < T; ++it) {
        if (it + 1 < T) {
            const float* Hs = Hsrc + (size_t)(it + 1) * BK * B_DIM;
            GLD_LDS16(Hs,             &Bs[nxt][wav * 4 + 0][0]);
            GLD_LDS16(Hs + 2 * B_DIM, &Bs[nxt][wav * 4 + 2][0]);
            asm volatile("s_waitcnt vmcnt(2)" ::: "memory");
        } else {
            asm volatile("s_waitcnt vmcnt(0)" ::: "memory");
        }
        __builtin_amdgcn_s_barrier();
        __builtin_amdgcn_sched_barrier(0);
        const int kb = it * BK;
#pragma unroll
        for (int q = 0; q < 4; ++q) {
            float ak[4][8];   // [s][i] from W
#pragma unroll
            for (int i = 0; i < 4; i++) {
                float4 v0 = *(const float4*)(W0 + (size_t)i * H_DIM + kb + q * 4);
                float4 v1 = *(const float4*)(W1 + (size_t)i * H_DIM + kb + q * 4);
                ak[0][i] = v0.x; ak[1][i] = v0.y; ak[2][i] = v0.z; ak[3][i] = v0.w;
                ak[0][i + 4] = v1.x; ak[1][i + 4] = v1.y; ak[2][i + 4] = v1.z; ak[3][i + 4] = v1.w;
            }
#pragma unroll
            for (int s = 0; s < 4; ++s) {
                const int k = q * 4 + s;
                float4 ya = *(const float4*)(&Bs[cur][k][tx * 4]);
                float4 yb = *(const float4*)(&Bs[cur][k][64 + tx * 4]);
                float bb[8] = {ya.x, ya.y, ya.z, ya.w, yb.x, yb.y, yb.z, yb.w};
#pragma unroll
                for (int i = 0; i < 8; i++)
#pragma unroll
                    for (int j = 0; j < 8; j++)
                        part[i][j] = fmaf(ak[s][i], bb[j], part[i][j]);
            }
        }
        cur = nxt;
        nxt = (nxt == 2) ? 0 : nxt + 1;
    }

    float* Pout = (pan == 0) ? P0 : (Prest + (size_t)(pan - 1) * B_DIM * V_DIM);
#pragma unroll
    for (int j = 0; j < 8; j++) {
        const int bcol = bb0 + ((j < 4) ? (tx * 4 + j) : (64 + tx * 4 + (j - 4)));
        float4 lo, hi;
        lo.x = part[0][j]; lo.y = part[1][j]; lo.z = part[2][j]; lo.w = part[3][j];
        hi.x = part[4][j]; hi.y = part[5][j]; hi.z = part[6][j]; hi.w = part[7][j];
        *(float4*)(&Pout[(size_t)bcol * V_DIM + bi + ty * 4])      = lo;
        *(float4*)(&Pout[(size_t)bcol * V_DIM + bi + 64 + ty * 4]) = hi;
    }
}

// ---------------------------------------------------------------------------
// h-side combine: tot = ((p0+p1)+...)+p10 ascending (bit-exact fold), then
// pre = bh + tot; h = (sigmoid(pre) > U). Hout may alias P0.
// ---------------------------------------------------------------------------
__global__ __launch_bounds__(256) void combine_h(
    const float* P0,               // [B_DIM, H_DIM] (may alias Hout)
    const float* __restrict__ Prest,
    const float* __restrict__ bh,
    const float* __restrict__ U,
    float* Hout,
    double* __restrict__ acc,      // direct store (single writer) or nullptr
    const int mode)
{
    const int b = blockIdx.x;
    const int c = threadIdx.x * 4;
    const size_t BH  = (size_t)B_DIM * H_DIM;
    const size_t off = (size_t)b * H_DIM + c;

    float4 tot = *(const float4*)(P0 + off);
#pragma unroll
    for (int p = 1; p < NPANEL_H; p++) {
        float4 q = *(const float4*)(Prest + (size_t)(p - 1) * BH + off);
        tot.x += q.x; tot.y += q.y; tot.z += q.z; tot.w += q.w;
    }
    float4 bias = *(const float4*)(bh + c);
    float4 u    = *(const float4*)(U + off);

    float pre[4] = {bias.x + tot.x, bias.y + tot.y, bias.z + tot.z, bias.w + tot.w};
    float bb[4]  = {bias.x, bias.y, bias.z, bias.w};
    float uu[4]  = {u.x, u.y, u.z, u.w};
    float hv[4];
#pragma unroll
    for (int j = 0; j < 4; j++) {
        float pp = 1.0f / (1.0f + expf(-pre[j]));
        hv[j] = (pp > uu[j]) ? 1.0f : 0.0f;
    }
    float4 hout; hout.x = hv[0]; hout.y = hv[1]; hout.z = hv[2]; hout.w = hv[3];
    *(float4*)(Hout + off) = hout;

    if (mode != ACC_NONE) {
        double s = 0.0;
#pragma unroll
        for (int j = 0; j < 4; j++) {
            if (mode == ACC_PREACT) s += (double)hv[j] * (double)pre[j];
            else                    s += (double)hv[j] * (double)bb[j];
        }
#pragma unroll
        for (int offl = 32; offl >= 1; offl >>= 1) s += __shfl_xor(s, offl, 64);
        __shared__ double red[4];
        if ((threadIdx.x & 63) == 0) red[threadIdx.x >> 6] = s;
        __syncthreads();
        if (threadIdx.x == 0) acc[b] = red[0] + red[1] + red[2] + red[3];
    }
}

// ---------------------------------------------------------------------------
// v-side combine: tot = (p0+p1)+p2 ascending; pre = bv + tot; v = (sig > U).
// Vout may alias P0. One block per row; 16 cols/thread in 4 chunks.
// ---------------------------------------------------------------------------
__global__ __launch_bounds__(256) void combine_v(
    const float* P0,               // [B_DIM, V_DIM] (may alias Vout)
    const float* __restrict__ Prest,
    const float* __restrict__ bv,
    const float* __restrict__ U,
    float* Vout,
    double* __restrict__ acc,
    const int mode)
{
    const int b = blockIdx.x;
    const size_t BV = (size_t)B_DIM * V_DIM;
    double s = 0.0;

#pragma unroll
    for (int ch = 0; ch < 4; ++ch) {
        const int c = ch * 1024 + threadIdx.x * 4;
        const size_t off = (size_t)b * V_DIM + c;
        float4 tot = *(const float4*)(P0 + off);
        float4 q1  = *(const float4*)(Prest + off);
        float4 q2  = *(const float4*)(Prest + BV + off);
        tot.x += q1.x; tot.y += q1.y; tot.z += q1.z; tot.w += q1.w;
        tot.x += q2.x; tot.y += q2.y; tot.z += q2.z; tot.w += q2.w;

        float4 bias = *(const float4*)(bv + c);
        float4 u4   = *(const float4*)(U + off);
        float pre[4] = {bias.x + tot.x, bias.y + tot.y, bias.z + tot.z, bias.w + tot.w};
        float uu[4]  = {u4.x, u4.y, u4.z, u4.w};
        float vs[4];
#pragma unroll
        for (int j = 0; j < 4; j++) {
            float pp = 1.0f / (1.0f + expf(-pre[j]));
            vs[j] = (pp > uu[j]) ? 1.0f : 0.0f;
            if (mode == ACC_PREACT) s += (double)vs[j] * (double)pre[j];
        }
        float4 vst; vst.x = vs[0]; vst.y = vs[1]; vst.z = vs[2]; vst.w = vs[3];
        *(float4*)(Vout + off) = vst;
    }

    if (mode != ACC_NONE) {
#pragma unroll
        for (int offl = 32; offl >= 1; offl >>= 1) s += __shfl_xor(s, offl, 64);
        __shared__ double red[4];
        if ((threadIdx.x & 63) == 0) red[threadIdx.x >> 6] = s;
        __syncthreads();
        if (threadIdx.x == 0) acc[b] = red[0] + red[1] + red[2] + red[3];
    }
}

// out[b] = sum_i X[b,i] * w[i] in fp64 (score term; does not feed sampling)
__global__ __launch_bounds__(256) void rowdot_kernel(
    const float* __restrict__ X, const float* __restrict__ w,
    double* __restrict__ out, const int N)
{
    const int b = blockIdx.x;
    const float* row = X + (size_t)b * N;
    double s = 0.0;
    for (int i = threadIdx.x; i < N / 4; i += blockDim.x) {
        float4 x = ((const float4*)row)[i];
        float4 ww = ((const float4*)w)[i];
        s = fma((double)x.x, (double)ww.x, s);
        s = fma((double)x.y, (double)ww.y, s);
        s = fma((double)x.z, (double)ww.z, s);
        s = fma((double)x.w, (double)ww.w, s);
    }
#pragma unroll
    for (int off = 32; off >= 1; off >>= 1) s += __shfl_xor(s, off, 64);
    __shared__ double red[4];
    if ((threadIdx.x & 63) == 0) red[threadIdx.x >> 6] = s;
    __syncthreads();
    if (threadIdx.x == 0) out[b] = red[0] + red[1] + red[2] + red[3];
}

__global__ void finalize_kernel(const double* __restrict__ vb,
                                const double* __restrict__ accpos,
                                const double* __restrict__ acchb,
                                const double* __restrict__ accneg,
                                float* __restrict__ out)
{
    int b = blockIdx.x * blockDim.x + threadIdx.x;
    if (b < B_DIM) out[b] = (float)(vb[b] + accpos[b] - acchb[b] - accneg[b]);
}

extern "C" void kernel_launch(void* const* d_in, const int* in_sizes, int n_in,
                              void* d_out, int out_size, void* d_ws, size_t ws_size,
                              hipStream_t stream) {
    (void)in_sizes; (void)n_in; (void)out_size; (void)ws_size;
    const float* visible = (const float*)d_in[0];
    const float* b_v     = (const float*)d_in[1];
    const float* b_h     = (const float*)d_in[2];
    const float* W       = (const float*)d_in[3];
    const float* u_h0    = (const float*)d_in[4];
    const float* u_v     = (const float*)d_in[5];  // [3, B, V]
    const float* u_h     = (const float*)d_in[6];  // [2, B, H]
    float* out = (float*)d_out;

    float* v_buf   = (float*)d_ws;                               // B*V floats
    float* h_buf   = v_buf + (size_t)B_DIM * V_DIM;              // B*H floats
    double* acc_pos = (double*)(h_buf + (size_t)B_DIM * H_DIM);  // B doubles
    double* acc_hb  = acc_pos + B_DIM;
    double* acc_neg = acc_hb + B_DIM;
    double* vb      = acc_neg + B_DIM;
    // shared extra-panel region: max(10*B*H, 2*B*V) = 20,971,520 floats (~84 MB)
    float* Pextra   = (float*)(vb + B_DIM);
    // hT [H_DIM, B_DIM] after Pextra (~8 MB); total ws ~134 MB (= round-1 proven)
    float* hT       = Pextra + (size_t)10 * B_DIM * H_DIM;

    dim3 blk(256);
    dim3 gh(H_DIM / BN, B_DIM / BM, NPANEL_H);   // 8 x 16 x 11 = 1408 blocks
    dim3 gv(V_DIM / BM, B_DIM / BN, NPANEL_V);   // 32 x 16 x 3 = 1536 blocks
    dim3 gt(H_DIM / 64, B_DIM / 64);             // 16 x 32 transpose blocks
    dim3 gc(B_DIM);

    rowdot_kernel<<<B_DIM, blk, 0, stream>>>(visible, b_v, vb, V_DIM);

    const size_t UV = (size_t)B_DIM * V_DIM;
    const size_t UH = (size_t)B_DIM * H_DIM;

    // positive phase: h | data, + sum h*pre
    gemm_h_panel<<<gh, blk, 0, stream>>>(visible, W, h_buf, Pextra);
    combine_h<<<gc, blk, 0, stream>>>(h_buf, Pextra, b_h, u_h0, h_buf, acc_pos, ACC_PREACT);
    // k=0
    transpose_kernel<<<gt, blk, 0, stream>>>(h_buf, hT);
    gemm_vT_panel<<<gv, blk, 0, stream>>>(W, hT, v_buf, Pextra);
    combine_v<<<gc, blk, 0, stream>>>(v_buf, Pextra, b_v, u_v + 0 * UV, v_buf, nullptr, ACC_NONE);
    // k=1
    gemm_h_panel<<<gh, blk, 0, stream>>>(v_buf, W, h_buf, Pextra);
    combine_h<<<gc, blk, 0, stream>>>(h_buf, Pextra, b_h, u_h + 0 * UH, h_buf, nullptr, ACC_NONE);
    // k=2
    transpose_kernel<<<gt, blk, 0, stream>>>(h_buf, hT);
    gemm_vT_panel<<<gv, blk, 0, stream>>>(W, hT, v_buf, Pextra);
    combine_v<<<gc, blk, 0, stream>>>(v_buf, Pextra, b_v, u_v + 1 * UV, v_buf, nullptr, ACC_NONE);
    // k=3: + h.b_h of final h
    gemm_h_panel<<<gh, blk, 0, stream>>>(v_buf, W, h_buf, Pextra);
    combine_h<<<gc, blk, 0, stream>>>(h_buf, Pextra, b_h, u_h + 1 * UH, h_buf, acc_hb, ACC_BIAS);
    // k=4: + sum_i v*pre (negative score)
    transpose_kernel<<<gt, blk, 0, stream>>>(h_buf, hT);
    gemm_vT_panel<<<gv, blk, 0, stream>>>(W, hT, v_buf, Pextra);
    combine_v<<<gc, blk, 0, stream>>>(v_buf, Pextra, b_v, u_v + 2 * UV, v_buf, acc_neg, ACC_PREACT);

    finalize_kernel<<<(B_DIM + 255) / 256, blk, 0, stream>>>(vb, acc_pos, acc_hb, acc_neg, out);
}